// Round 6
// baseline (883.971 us; speedup 1.0000x reference)
//
#include <hip/hip_runtime.h>

// 2-layer tanh RNN, B=2048 T=512 I=5 H=64 O=1.
// One wave64 per batch element (2048 waves = 2/SIMD). Lane i owns h1[i],
// h2[i] and row i of W_hh0/W_ih1/W_hh1 in VGPRs. Cross-lane broadcast via
// v_readlane -> SGPR feeding v_fmac src0 (2 VALU ops per 64-MAC group).
//
// R5 post-mortem (absmax 6.25e-2): VALU-writes-VGPR -> lane-crossing-read
// hazard. tanh's final v_mul writes h1; the first v_readlane of the next
// asm block reads it with zero spacing. The HW needs software wait states
// (DPP-family hazard); the compiler can't see inside inline asm to insert
// them. Fixes: (1) e-blocks (h2-old) reordered BEFORE c-blocks (h1-new) --
// 128 instrs of structural spacing after h1's def; (2) s_nop 1 leads every
// DOT8 (covers any producer->readlane adjacency, ~5% cost); (3) volatile
// pins block order.

constexpr int Bn = 2048;
constexpr int Tn = 512;
constexpr int In = 5;
constexpr int Hn = 64;

// 8 MACs: acc{0..3} += W[L..L+7] * broadcast(H from lanes L..L+7).
// s_nop 1 = 2 wait states kills VALU->readlane hazards at block entry;
// readlanes sit 8 instrs ahead of their consuming fmacs (SGPR hazard-safe).
#define DOT8(A0, A1, A2, A3, Hreg, W, L)                                     \
  do {                                                                       \
    float s0, s1, s2, s3, s4, s5, s6, s7;                                    \
    asm volatile(                                                            \
        "s_nop 1\n\t"                                                        \
        "v_readlane_b32 %4, %12, %13\n\t"                                    \
        "v_readlane_b32 %5, %12, %14\n\t"                                    \
        "v_readlane_b32 %6, %12, %15\n\t"                                    \
        "v_readlane_b32 %7, %12, %16\n\t"                                    \
        "v_readlane_b32 %8, %12, %17\n\t"                                    \
        "v_readlane_b32 %9, %12, %18\n\t"                                    \
        "v_readlane_b32 %10, %12, %19\n\t"                                   \
        "v_readlane_b32 %11, %12, %20\n\t"                                   \
        "v_fmac_f32 %0, %4, %21\n\t"                                         \
        "v_fmac_f32 %1, %5, %22\n\t"                                         \
        "v_fmac_f32 %2, %6, %23\n\t"                                         \
        "v_fmac_f32 %3, %7, %24\n\t"                                         \
        "v_fmac_f32 %0, %8, %25\n\t"                                         \
        "v_fmac_f32 %1, %9, %26\n\t"                                         \
        "v_fmac_f32 %2, %10, %27\n\t"                                        \
        "v_fmac_f32 %3, %11, %28"                                            \
        : "+v"(A0), "+v"(A1), "+v"(A2), "+v"(A3),                            \
          "=s"(s0), "=s"(s1), "=s"(s2), "=s"(s3),                            \
          "=s"(s4), "=s"(s5), "=s"(s6), "=s"(s7)                             \
        : "v"(Hreg),                                                         \
          "i"((L) + 0), "i"((L) + 1), "i"((L) + 2), "i"((L) + 3),            \
          "i"((L) + 4), "i"((L) + 5), "i"((L) + 6), "i"((L) + 7),            \
          "v"((W)[(L) + 0]), "v"((W)[(L) + 1]), "v"((W)[(L) + 2]),           \
          "v"((W)[(L) + 3]), "v"((W)[(L) + 4]), "v"((W)[(L) + 5]),           \
          "v"((W)[(L) + 6]), "v"((W)[(L) + 7]));                             \
  } while (0)

// tanh(v) = (e-1)/(e+1), e = 2^(2*log2(e)*v); med3 clamp stops overflow.
__device__ __forceinline__ float fast_tanh(float v) {
    v = __builtin_amdgcn_fmed3f(v, -15.f, 15.f);
    float e = __builtin_amdgcn_exp2f(v * 2.885390082f);
    return (e - 1.f) * __builtin_amdgcn_rcpf(e + 1.f);
}

__device__ __forceinline__ void pin(float& v) {
    asm volatile("" : "+v"(v));
}

__global__ __launch_bounds__(256, 2) void rnn2_fused(
    const float* __restrict__ x,
    const float* __restrict__ W_ih0, const float* __restrict__ W_hh0,
    const float* __restrict__ b_ih0, const float* __restrict__ b_hh0,
    const float* __restrict__ W_ih1, const float* __restrict__ W_hh1,
    const float* __restrict__ b_ih1, const float* __restrict__ b_hh1,
    const float* __restrict__ fc_W, const float* __restrict__ fc_b,
    float* __restrict__ out)
{
    const int lane = threadIdx.x & 63;
    int b = (blockIdx.x << 2) + (threadIdx.x >> 6);
    b = __builtin_amdgcn_readfirstlane(b);   // wave-uniform -> scalar x loads

    // ---- stage weights into per-lane registers (rows of each matrix) ----
    float wih0[In];
    #pragma unroll
    for (int j = 0; j < In; ++j) wih0[j] = W_ih0[lane * In + j];

    float whh0[Hn], wih1[Hn], whh1[Hn];
    {
        const float4* p0 = reinterpret_cast<const float4*>(W_hh0) + lane * (Hn / 4);
        const float4* p1 = reinterpret_cast<const float4*>(W_ih1) + lane * (Hn / 4);
        const float4* p2 = reinterpret_cast<const float4*>(W_hh1) + lane * (Hn / 4);
        #pragma unroll
        for (int k = 0; k < Hn / 4; ++k) {
            float4 v0 = p0[k];
            whh0[4*k+0] = v0.x; whh0[4*k+1] = v0.y; whh0[4*k+2] = v0.z; whh0[4*k+3] = v0.w;
            float4 v1 = p1[k];
            wih1[4*k+0] = v1.x; wih1[4*k+1] = v1.y; wih1[4*k+2] = v1.z; wih1[4*k+3] = v1.w;
            float4 v2 = p2[k];
            whh1[4*k+0] = v2.x; whh1[4*k+1] = v2.y; whh1[4*k+2] = v2.z; whh1[4*k+3] = v2.w;
        }
    }
    #pragma unroll
    for (int j = 0; j < In; ++j) pin(wih0[j]);
    #pragma unroll
    for (int j = 0; j < Hn; ++j) { pin(whh0[j]); pin(wih1[j]); pin(whh1[j]); }

    const float bias0 = b_ih0[lane] + b_hh0[lane];
    const float bias1 = b_ih1[lane] + b_hh1[lane];

    float h1 = 0.f, h2 = 0.f;

    const float* xp = x + (size_t)b * (Tn * In);
    float xv[In];
    #pragma unroll
    for (int j = 0; j < In; ++j) xv[j] = xp[j];

    #pragma unroll 1
    for (int t = 0; t < Tn; ++t) {
        // prefetch next step's x (uniform/scalar) a full step early
        const int tn = (t + 1 < Tn) ? (t + 1) : (Tn - 1);
        const float* xq = xp + tn * In;
        float xn[In];
        #pragma unroll
        for (int j = 0; j < In; ++j) xn[j] = xq[j];

        // ---- layer 1: h1 = tanh(Wih0 x_t + Whh0 h1_old + b) ----
        float a0 = bias0, a1 = 0.f, a2 = 0.f, a3 = 0.f;
        #pragma unroll
        for (int j = 0; j < In; ++j) a0 += wih0[j] * xv[j];
        DOT8(a0, a1, a2, a3, h1, whh0, 0);
        DOT8(a0, a1, a2, a3, h1, whh0, 8);
        DOT8(a0, a1, a2, a3, h1, whh0, 16);
        DOT8(a0, a1, a2, a3, h1, whh0, 24);
        DOT8(a0, a1, a2, a3, h1, whh0, 32);
        DOT8(a0, a1, a2, a3, h1, whh0, 40);
        DOT8(a0, a1, a2, a3, h1, whh0, 48);
        DOT8(a0, a1, a2, a3, h1, whh0, 56);
        h1 = fast_tanh((a0 + a1) + (a2 + a3));

        // ---- layer 2: h2 = tanh(Wih1 h1_new + Whh1 h2_old + b) ----
        // e-blocks (h2_old) FIRST: 128 instrs of spacing between h1's
        // producing VALU op and the first readlane of h1 (c-blocks).
        float e0 = 0.f, e1 = 0.f, e2 = 0.f, e3 = 0.f;     // whh1 . h2_old
        DOT8(e0, e1, e2, e3, h2, whh1, 0);
        DOT8(e0, e1, e2, e3, h2, whh1, 8);
        DOT8(e0, e1, e2, e3, h2, whh1, 16);
        DOT8(e0, e1, e2, e3, h2, whh1, 24);
        DOT8(e0, e1, e2, e3, h2, whh1, 32);
        DOT8(e0, e1, e2, e3, h2, whh1, 40);
        DOT8(e0, e1, e2, e3, h2, whh1, 48);
        DOT8(e0, e1, e2, e3, h2, whh1, 56);
        float c0 = bias1, c1 = 0.f, c2 = 0.f, c3 = 0.f;   // wih1 . h1_new
        DOT8(c0, c1, c2, c3, h1, wih1, 0);
        DOT8(c0, c1, c2, c3, h1, wih1, 8);
        DOT8(c0, c1, c2, c3, h1, wih1, 16);
        DOT8(c0, c1, c2, c3, h1, wih1, 24);
        DOT8(c0, c1, c2, c3, h1, wih1, 32);
        DOT8(c0, c1, c2, c3, h1, wih1, 40);
        DOT8(c0, c1, c2, c3, h1, wih1, 48);
        DOT8(c0, c1, c2, c3, h1, wih1, 56);
        h2 = fast_tanh(((c0 + c1) + (c2 + c3)) + ((e0 + e1) + (e2 + e3)));

        #pragma unroll
        for (int j = 0; j < In; ++j) xv[j] = xn[j];
    }

    // ---- fc: out[b] = fc_W . h2 + fc_b ----
    float contrib = fc_W[lane] * h2;
    #pragma unroll
    for (int off = 32; off; off >>= 1)
        contrib += __shfl_xor(contrib, off, 64);
    if (lane == 0) out[b] = contrib + fc_b[0];
}

extern "C" void kernel_launch(void* const* d_in, const int* in_sizes, int n_in,
                              void* d_out, int out_size, void* d_ws, size_t ws_size,
                              hipStream_t stream) {
    const float* x     = (const float*)d_in[0];
    const float* W_ih0 = (const float*)d_in[1];
    const float* W_hh0 = (const float*)d_in[2];
    const float* b_ih0 = (const float*)d_in[3];
    const float* b_hh0 = (const float*)d_in[4];
    const float* W_ih1 = (const float*)d_in[5];
    const float* W_hh1 = (const float*)d_in[6];
    const float* b_ih1 = (const float*)d_in[7];
    const float* b_hh1 = (const float*)d_in[8];
    const float* fc_W  = (const float*)d_in[9];
    const float* fc_b  = (const float*)d_in[10];
    float* out = (float*)d_out;

    dim3 grid(Bn / 4);   // 512 blocks x 4 waves = 2048 waves, one per batch
    dim3 block(256);
    hipLaunchKernelGGL(rnn2_fused, grid, block, 0, stream,
                       x, W_ih0, W_hh0, b_ih0, b_hh0,
                       W_ih1, W_hh1, b_ih1, b_hh1, fc_W, fc_b, out);
}

// Round 9
// 565.899 us; speedup vs baseline: 1.5621x; 1.5621x over previous
//
#include <hip/hip_runtime.h>

// 2-layer tanh RNN, B=2048 T=512 I=5 H=64 O=1 — MFMA formulation.
//
// Per step, per wave (owns 16 batch columns, all 64 h rows):
//   S1^T[64h x 16b] = Wih0[64x5pad16] @ X^T + Whh0[64x64] @ H1^T   (+bias via C-init)
//   h1 = tanh(S1);   S2^T = Wih1 @ H1new^T + Whh1 @ H2^T;  h2 = tanh(S2)
// using v_mfma_f32_16x16x16_f16 tiles (M-tiles m=0..3, K-tiles kk=0..3).
//
// Layout identity that makes feedback FREE (m89-verified C/D = canonical B):
//   C/D: row=(l>>4)*4+r, col=l&15   ==   B: k=(l>>4)*4+e, col=l&15
// so tanh(D) -> cvt f16 (RNE) -> pack pairs IS next step's B frag, lane-local.
// No readlanes, no LDS, no barriers, no inline asm (compiler manages hazards).
//
// R7 fix: builtin spelling is __builtin_amdgcn_mfma_f32_16x16x16f16 (no
// underscore before f16) in BOTH host and device passes.
// R8: infra failure (container died twice) — identical source resubmitted.

constexpr int Bn = 2048;
constexpr int Tn = 512;
constexpr int In = 5;
constexpr int Hn = 64;

typedef _Float16 half4 __attribute__((ext_vector_type(4)));
typedef float f32x4 __attribute__((ext_vector_type(4)));

#define MFMA16(A, B, C) __builtin_amdgcn_mfma_f32_16x16x16f16((A), (B), (C), 0, 0, 0)

__device__ __forceinline__ unsigned pk(float a, float b) {   // 2x f32 -> packed f16 (RNE)
    union { _Float16 h[2]; unsigned u; } z;
    z.h[0] = (_Float16)a; z.h[1] = (_Float16)b;
    return z.u;
}
__device__ __forceinline__ half4 mkh4(unsigned a, unsigned b) {
    union { unsigned u[2]; half4 h; } z; z.u[0] = a; z.u[1] = b; return z.h;
}
__device__ __forceinline__ float flo(unsigned w) {
    union { unsigned u; _Float16 h[2]; } z; z.u = w; return (float)z.h[0];
}
__device__ __forceinline__ float fhi(unsigned w) {
    union { unsigned u; _Float16 h[2]; } z; z.u = w; return (float)z.h[1];
}

// tanh(v) = (e-1)/(e+1), e = 2^(2*log2e*v); med3 clamp stops overflow.
__device__ __forceinline__ float fast_tanh(float v) {
    v = __builtin_amdgcn_fmed3f(v, -15.f, 15.f);
    float e = __builtin_amdgcn_exp2f(v * 2.885390082f);
    return (e - 1.f) * __builtin_amdgcn_rcpf(e + 1.f);
}

__global__ __launch_bounds__(64, 1) void rnn2_mfma(
    const float* __restrict__ x,
    const float* __restrict__ W_ih0, const float* __restrict__ W_hh0,
    const float* __restrict__ b_ih0, const float* __restrict__ b_hh0,
    const float* __restrict__ W_ih1, const float* __restrict__ W_hh1,
    const float* __restrict__ b_ih1, const float* __restrict__ b_hh1,
    const float* __restrict__ fc_W, const float* __restrict__ fc_b,
    float* __restrict__ out)
{
    const int tid = threadIdx.x;
    const int q = tid >> 4;        // lane quarter: selects k-window / row-group
    const int c = tid & 15;        // column within tile = batch offset / A-row
    const int b0 = blockIdx.x * 16;

    // ---- one-time: weight A-frags. A[row=c][k=q*4+e] per (m,kk) tile ----
    half4 A_ih0[4];                // K-tile 0 only (k=0..4 real, rest 0)
    half4 A_hh0[4][4], A_ih1[4][4], A_hh1[4][4];
    #pragma unroll
    for (int m = 0; m < 4; ++m) {
        {   // W_ih0 is [64][5] row-major; rows stride 20B -> scalar loads
            unsigned a0 = 0, a1 = 0;
            const float* p = W_ih0 + (m * 16 + c) * In;
            if (q == 0)      { a0 = pk(p[0], p[1]); a1 = pk(p[2], p[3]); }
            else if (q == 1) { a0 = pk(p[4], 0.f); }
            A_ih0[m] = mkh4(a0, a1);
        }
        #pragma unroll
        for (int kk = 0; kk < 4; ++kk) {
            const int off = (m * 16 + c) * Hn + kk * 16 + q * 4;  // 16B aligned
            float4 w0 = *reinterpret_cast<const float4*>(W_hh0 + off);
            A_hh0[m][kk] = mkh4(pk(w0.x, w0.y), pk(w0.z, w0.w));
            float4 w1 = *reinterpret_cast<const float4*>(W_ih1 + off);
            A_ih1[m][kk] = mkh4(pk(w1.x, w1.y), pk(w1.z, w1.w));
            float4 w2 = *reinterpret_cast<const float4*>(W_hh1 + off);
            A_hh1[m][kk] = mkh4(pk(w2.x, w2.y), pk(w2.z, w2.w));
        }
    }

    // ---- one-time: bias C-init frags (C layout: row = m*16 + q*4 + r) ----
    f32x4 bc1[4], bc2[4];
    #pragma unroll
    for (int m = 0; m < 4; ++m)
        #pragma unroll
        for (int r = 0; r < 4; ++r) {
            const int row = m * 16 + q * 4 + r;
            bc1[m][r] = b_ih0[row] + b_hh0[row];
            bc2[m][r] = b_ih1[row] + b_hh1[row];
        }

    // ---- state: h as B-frag words. h?f[kk][j] = f16 pair of
    //      h[k = 16*kk + q*4 + 2j (lo), +1 (hi)][batch b0+c]; h0 = 0 ----
    unsigned h1f[4][2] = {{0,0},{0,0},{0,0},{0,0}};
    unsigned h2f[4][2] = {{0,0},{0,0},{0,0},{0,0}};

    const float* xrow = x + (size_t)(b0 + c) * Tn * In;

    // prefetch x(t=0): q0 lanes carry x0..3, q1 lanes carry x4 (rows 20B, scalar)
    float nx0 = 0.f, nx1 = 0.f, nx2 = 0.f, nx3 = 0.f, nx4 = 0.f;
    if (q == 0)      { nx0 = xrow[0]; nx1 = xrow[1]; nx2 = xrow[2]; nx3 = xrow[3]; }
    else if (q == 1) { nx4 = xrow[4]; }

    #pragma unroll 1
    for (int t = 0; t < Tn; ++t) {
        // x B-frag for this step: k=q*4+e -> q0: x0..x3, q1: {x4,0,0,0}
        unsigned r0 = (q == 0) ? pk(nx0, nx1) : ((q == 1) ? pk(nx4, 0.f) : 0u);
        unsigned r1 = (q == 0) ? pk(nx2, nx3) : 0u;
        const half4 XF = mkh4(r0, r1);

        // prefetch x(t+1) under this step's compute
        const int tn = (t + 1 < Tn) ? (t + 1) : (Tn - 1);
        const float* xp = xrow + tn * In;
        if (q == 0)      { nx0 = xp[0]; nx1 = xp[1]; nx2 = xp[2]; nx3 = xp[3]; }
        else if (q == 1) { nx4 = xp[4]; }

        f32x4 a[4];

        // ---- layer 1: S1^T tiles ----
        #pragma unroll
        for (int m = 0; m < 4; ++m) {
            f32x4 acc = bc1[m];
            acc = MFMA16(A_ih0[m], XF, acc);
            #pragma unroll
            for (int kk = 0; kk < 4; ++kk)
                acc = MFMA16(A_hh0[m][kk], mkh4(h1f[kk][0], h1f[kk][1]), acc);
            a[m] = acc;
        }
        // tanh + repack -> new h1 frags (lane-local: C row == B k)
        #pragma unroll
        for (int m = 0; m < 4; ++m) {
            float t0 = fast_tanh(a[m][0]), t1 = fast_tanh(a[m][1]);
            float t2 = fast_tanh(a[m][2]), t3 = fast_tanh(a[m][3]);
            h1f[m][0] = pk(t0, t1); h1f[m][1] = pk(t2, t3);
        }

        // ---- layer 2: S2^T tiles (h1 new, h2 old) ----
        #pragma unroll
        for (int m = 0; m < 4; ++m) {
            f32x4 acc = bc2[m];
            #pragma unroll
            for (int kk = 0; kk < 4; ++kk)
                acc = MFMA16(A_ih1[m][kk], mkh4(h1f[kk][0], h1f[kk][1]), acc);
            #pragma unroll
            for (int kk = 0; kk < 4; ++kk)
                acc = MFMA16(A_hh1[m][kk], mkh4(h2f[kk][0], h2f[kk][1]), acc);
            a[m] = acc;
        }
        #pragma unroll
        for (int m = 0; m < 4; ++m) {
            float t0 = fast_tanh(a[m][0]), t1 = fast_tanh(a[m][1]);
            float t2 = fast_tanh(a[m][2]), t3 = fast_tanh(a[m][3]);
            h2f[m][0] = pk(t0, t1); h2f[m][1] = pk(t2, t3);
        }
    }

    // ---- fc: out[b0+c] = sum_k fc_W[k]*h2[k][c] + fc_b ----
    float s = 0.f;
    #pragma unroll
    for (int kk = 0; kk < 4; ++kk) {
        const int kbase = 16 * kk + q * 4;
        s += flo(h2f[kk][0]) * fc_W[kbase + 0];
        s += fhi(h2f[kk][0]) * fc_W[kbase + 1];
        s += flo(h2f[kk][1]) * fc_W[kbase + 2];
        s += fhi(h2f[kk][1]) * fc_W[kbase + 3];
    }
    s += __shfl_xor(s, 16, 64);   // combine quarters (k-groups)
    s += __shfl_xor(s, 32, 64);
    if (tid < 16) out[b0 + tid] = s + fc_b[0];
}

extern "C" void kernel_launch(void* const* d_in, const int* in_sizes, int n_in,
                              void* d_out, int out_size, void* d_ws, size_t ws_size,
                              hipStream_t stream) {
    const float* x     = (const float*)d_in[0];
    const float* W_ih0 = (const float*)d_in[1];
    const float* W_hh0 = (const float*)d_in[2];
    const float* b_ih0 = (const float*)d_in[3];
    const float* b_hh0 = (const float*)d_in[4];
    const float* W_ih1 = (const float*)d_in[5];
    const float* W_hh1 = (const float*)d_in[6];
    const float* b_ih1 = (const float*)d_in[7];
    const float* b_hh1 = (const float*)d_in[8];
    const float* fc_W  = (const float*)d_in[9];
    const float* fc_b  = (const float*)d_in[10];
    float* out = (float*)d_out;

    dim3 grid(Bn / 16);   // 128 waves, each owns 16 batch columns
    dim3 block(64);
    hipLaunchKernelGGL(rnn2_mfma, grid, block, 0, stream,
                       x, W_ih0, W_hh0, b_ih0, b_hh0,
                       W_ih1, W_hh1, b_ih1, b_hh1, fc_W, fc_b, out);
}

// Round 10
// 360.930 us; speedup vs baseline: 2.4491x; 1.5679x over previous
//
#include <hip/hip_runtime.h>

// 2-layer tanh RNN, B=2048 T=512 I=5 H=64 O=1 — MFMA + 4-wave M-split.
//
// R9 post-mortem: 1-wave-per-tile MFMA version = 494us, occupancy 1.5%,
// step time 2316 cyc vs ~200 cyc dependency floor — pure exposed-latency
// regime. Batch parallelism is exhausted (128 tiles); wall time = per-wave
// step critical path x 512. So: split the 64 h-rows across 4 waves/block
// (wave w owns rows 16w..16w+15): 13 MFMAs + 8 tanh per wave per step
// instead of 52 + 32.
//
// Exchange trick: C/D frag rows (l>>4)*4+r at col l&15 == B-frag k-slots
// (l>>4)*4+e at col l&15, so wave w's tanh'd C-tile IS K-tile w of the
// next B operand AT THE SAME LANE: exchange = ds_write_b64 buf[w][lane],
// ds_read_b64 buf[kt][lane]. No transpose, no repack, 2 barriers/step.
// h1 tiles read mid-step are register-carried into next step's layer 1.

constexpr int Bn = 2048;
constexpr int Tn = 512;
constexpr int In = 5;
constexpr int Hn = 64;

typedef _Float16 half4 __attribute__((ext_vector_type(4)));
typedef float f32x4 __attribute__((ext_vector_type(4)));

#define MFMA16(A, B, C) __builtin_amdgcn_mfma_f32_16x16x16f16((A), (B), (C), 0, 0, 0)

__device__ __forceinline__ unsigned pk(float a, float b) {   // 2x f32 -> packed f16 (RNE)
    union { _Float16 h[2]; unsigned u; } z;
    z.h[0] = (_Float16)a; z.h[1] = (_Float16)b;
    return z.u;
}
__device__ __forceinline__ half4 mkh4(unsigned a, unsigned b) {
    union { unsigned u[2]; half4 h; } z; z.u[0] = a; z.u[1] = b; return z.h;
}
__device__ __forceinline__ half4 h4of(unsigned long long v) {
    union { unsigned long long q; half4 h; } z; z.q = v; return z.h;
}

// tanh(v) = (e-1)/(e+1), e = 2^(2*log2e*v); med3 clamp stops overflow.
__device__ __forceinline__ float fast_tanh(float v) {
    v = __builtin_amdgcn_fmed3f(v, -15.f, 15.f);
    float e = __builtin_amdgcn_exp2f(v * 2.885390082f);
    return (e - 1.f) * __builtin_amdgcn_rcpf(e + 1.f);
}

__global__ __launch_bounds__(256) void rnn2_mfma4(
    const float* __restrict__ x,
    const float* __restrict__ W_ih0, const float* __restrict__ W_hh0,
    const float* __restrict__ b_ih0, const float* __restrict__ b_hh0,
    const float* __restrict__ W_ih1, const float* __restrict__ W_hh1,
    const float* __restrict__ b_ih1, const float* __restrict__ b_hh1,
    const float* __restrict__ fc_W, const float* __restrict__ fc_b,
    float* __restrict__ out)
{
    const int tid = threadIdx.x;
    const int w = tid >> 6;          // wave = M-slice owner (rows 16w..16w+15)
    const int l = tid & 63;
    const int q = l >> 4, c = l & 15;
    const int b0 = blockIdx.x * 16;
    const int row = w * 16 + c;      // this lane's A-fragment row

    __shared__ unsigned long long h1buf[2][4][64];   // [dbuf][ktile][lane]
    __shared__ unsigned long long h2buf[2][4][64];
    __shared__ float fcpart[4][16];

    // ---- A-frags for this wave's 16 output rows ----
    half4 A_ih0;
    {
        unsigned a0 = 0, a1 = 0;
        const float* p = W_ih0 + row * In;           // [64][5] row-major
        if (q == 0)      { a0 = pk(p[0], p[1]); a1 = pk(p[2], p[3]); }
        else if (q == 1) { a0 = pk(p[4], 0.f); }
        A_ih0 = mkh4(a0, a1);
    }
    half4 A_hh0[4], A_ih1[4], A_hh1[4];
    #pragma unroll
    for (int kt = 0; kt < 4; ++kt) {
        const int off = row * Hn + kt * 16 + q * 4;  // 16B aligned
        float4 v0 = *reinterpret_cast<const float4*>(W_hh0 + off);
        A_hh0[kt] = mkh4(pk(v0.x, v0.y), pk(v0.z, v0.w));
        float4 v1 = *reinterpret_cast<const float4*>(W_ih1 + off);
        A_ih1[kt] = mkh4(pk(v1.x, v1.y), pk(v1.z, v1.w));
        float4 v2 = *reinterpret_cast<const float4*>(W_hh1 + off);
        A_hh1[kt] = mkh4(pk(v2.x, v2.y), pk(v2.z, v2.w));
    }

    // ---- bias C-init (C row = 16w + q*4 + r) ----
    f32x4 bc1, bc2;
    #pragma unroll
    for (int r = 0; r < 4; ++r) {
        const int rr = w * 16 + q * 4 + r;
        bc1[r] = b_ih0[rr] + b_hh0[rr];
        bc2[r] = b_ih1[rr] + b_hh1[rr];
    }

    // ---- state: full-K B-frags, register-carried between steps ----
    unsigned long long h1B[4] = {0, 0, 0, 0};
    unsigned long long h2B[4] = {0, 0, 0, 0};
    f32x4 h2v = {0.f, 0.f, 0.f, 0.f};   // own h2 rows as f32 (for fc)

    const float* xrow = x + (size_t)(b0 + c) * Tn * In;
    float nx0 = 0.f, nx1 = 0.f, nx2 = 0.f, nx3 = 0.f, nx4 = 0.f;
    if (q == 0)      { nx0 = xrow[0]; nx1 = xrow[1]; nx2 = xrow[2]; nx3 = xrow[3]; }
    else if (q == 1) { nx4 = xrow[4]; }

    #pragma unroll 1
    for (int t = 0; t < Tn; ++t) {
        unsigned r0 = (q == 0) ? pk(nx0, nx1) : ((q == 1) ? pk(nx4, 0.f) : 0u);
        unsigned r1 = (q == 0) ? pk(nx2, nx3) : 0u;
        const half4 XF = mkh4(r0, r1);

        const int tn = (t + 1 < Tn) ? (t + 1) : (Tn - 1);
        const float* xp = xrow + tn * In;
        if (q == 0)      { nx0 = xp[0]; nx1 = xp[1]; nx2 = xp[2]; nx3 = xp[3]; }
        else if (q == 1) { nx4 = xp[4]; }

        // ---- layer 1 (regs only): S1 rows = ih0@X + hh0@h1_old ----
        f32x4 acc = bc1;
        acc = MFMA16(A_ih0, XF, acc);
        #pragma unroll
        for (int kt = 0; kt < 4; ++kt)
            acc = MFMA16(A_hh0[kt], h4of(h1B[kt]), acc);
        float t0 = fast_tanh(acc[0]), t1 = fast_tanh(acc[1]);
        float t2 = fast_tanh(acc[2]), t3 = fast_tanh(acc[3]);
        unsigned long long myh1 =
            (unsigned long long)pk(t0, t1) | ((unsigned long long)pk(t2, t3) << 32);

        // ---- exchange h1 (write own K-tile, read all) ----
        h1buf[t & 1][w][l] = myh1;
        __syncthreads();
        #pragma unroll
        for (int kt = 0; kt < 4; ++kt) h1B[kt] = h1buf[t & 1][kt][l];

        // ---- layer 2: two parallel 4-MFMA chains ----
        f32x4 aA = bc2;                    // ih1 @ h1_new
        f32x4 aB = {0.f, 0.f, 0.f, 0.f};   // hh1 @ h2_old
        #pragma unroll
        for (int kt = 0; kt < 4; ++kt) {
            aA = MFMA16(A_ih1[kt], h4of(h1B[kt]), aA);
            aB = MFMA16(A_hh1[kt], h4of(h2B[kt]), aB);
        }
        h2v[0] = fast_tanh(aA[0] + aB[0]); h2v[1] = fast_tanh(aA[1] + aB[1]);
        h2v[2] = fast_tanh(aA[2] + aB[2]); h2v[3] = fast_tanh(aA[3] + aB[3]);
        unsigned long long myh2 =
            (unsigned long long)pk(h2v[0], h2v[1]) | ((unsigned long long)pk(h2v[2], h2v[3]) << 32);

        // ---- exchange h2 (read latency hides under next step's layer 1) ----
        h2buf[t & 1][w][l] = myh2;
        __syncthreads();
        #pragma unroll
        for (int kt = 0; kt < 4; ++kt) h2B[kt] = h2buf[t & 1][kt][l];
    }

    // ---- fc: out[b0+c] = sum_k fc_W[k] * h2[k][c] + fc_b ----
    float s = 0.f;
    #pragma unroll
    for (int e = 0; e < 4; ++e)
        s += fc_W[w * 16 + q * 4 + e] * h2v[e];
    s += __shfl_xor(s, 16, 64);   // sum over q within wave
    s += __shfl_xor(s, 32, 64);
    if (l < 16) fcpart[w][l] = s;
    __syncthreads();
    if (tid < 16)
        out[b0 + tid] = fcpart[0][tid] + fcpart[1][tid] + fcpart[2][tid]
                      + fcpart[3][tid] + fc_b[0];
}

extern "C" void kernel_launch(void* const* d_in, const int* in_sizes, int n_in,
                              void* d_out, int out_size, void* d_ws, size_t ws_size,
                              hipStream_t stream) {
    const float* x     = (const float*)d_in[0];
    const float* W_ih0 = (const float*)d_in[1];
    const float* W_hh0 = (const float*)d_in[2];
    const float* b_ih0 = (const float*)d_in[3];
    const float* b_hh0 = (const float*)d_in[4];
    const float* W_ih1 = (const float*)d_in[5];
    const float* W_hh1 = (const float*)d_in[6];
    const float* b_ih1 = (const float*)d_in[7];
    const float* b_hh1 = (const float*)d_in[8];
    const float* fc_W  = (const float*)d_in[9];
    const float* fc_b  = (const float*)d_in[10];
    float* out = (float*)d_out;

    dim3 grid(Bn / 16);   // 128 blocks; 4 waves/block = 512 waves
    dim3 block(256);
    hipLaunchKernelGGL(rnn2_mfma4, grid, block, 0, stream,
                       x, W_ih0, W_hh0, b_ih0, b_hh0,
                       W_ih1, W_hh1, b_ih1, b_hh1, fc_W, fc_b, out);
}

// Round 12
// 310.003 us; speedup vs baseline: 2.8515x; 1.1643x over previous
//
#include <hip/hip_runtime.h>

// 2-layer tanh RNN, B=2048 T=512 I=5 H=64 O=1 — MFMA, layer-specialized
// wave pipeline.
//
// R10 post-mortem: 4-wave M-split = 291us = 1364 cyc/step; exposed serial
// path = L1(5 MFMA chain + tanh) + exchange + L2(4 MFMA chain + tanh) +
// exchange. MFMA dependent latency ~60-80cyc makes chain depth the cost.
//
// This version: waves 0-3 compute H1[t+1] (M-split, 5 MFMA in 3 parallel
// chains) WHILE waves 4-7 compute H2[t] (M-split, 8 MFMA in 4 parallel
// chains) — legal because H2[t] needs only H1[t] (read last iteration) and
// H2[t-1]. ONE barrier per iteration, double-buffered LDS exchange:
//   write buf[t&1] -> barrier -> read buf[t&1]; next iter writes buf[~t&1].
// T+1 iterations: L2 idles at t=0 (writes H2[0]=0), L1 idles at t=T.
//
// Exchange stays the free C->B layout identity (C/D row == B k-slot at the
// same lane): wave m's tanh'd C-tile IS K-tile m of the next B operand.
//
// R11: infra failure (GPU acquisition timeout) — identical source resubmitted.

constexpr int Bn = 2048;
constexpr int Tn = 512;
constexpr int In = 5;
constexpr int Hn = 64;

typedef _Float16 half4 __attribute__((ext_vector_type(4)));
typedef float f32x4 __attribute__((ext_vector_type(4)));

#define MFMA16(A, B, C) __builtin_amdgcn_mfma_f32_16x16x16f16((A), (B), (C), 0, 0, 0)

__device__ __forceinline__ unsigned pk(float a, float b) {   // 2x f32 -> packed f16 (RNE)
    union { _Float16 h[2]; unsigned u; } z;
    z.h[0] = (_Float16)a; z.h[1] = (_Float16)b;
    return z.u;
}
__device__ __forceinline__ half4 mkh4(unsigned a, unsigned b) {
    union { unsigned u[2]; half4 h; } z; z.u[0] = a; z.u[1] = b; return z.h;
}
__device__ __forceinline__ half4 h4of(unsigned long long v) {
    union { unsigned long long q; half4 h; } z; z.q = v; return z.h;
}

// tanh(v) = (e-1)/(e+1), e = 2^(2*log2e*v); med3 clamp stops overflow.
__device__ __forceinline__ float fast_tanh(float v) {
    v = __builtin_amdgcn_fmed3f(v, -15.f, 15.f);
    float e = __builtin_amdgcn_exp2f(v * 2.885390082f);
    return (e - 1.f) * __builtin_amdgcn_rcpf(e + 1.f);
}

__global__ __launch_bounds__(512, 1) void rnn2_pipe(
    const float* __restrict__ x,
    const float* __restrict__ W_ih0, const float* __restrict__ W_hh0,
    const float* __restrict__ b_ih0, const float* __restrict__ b_hh0,
    const float* __restrict__ W_ih1, const float* __restrict__ W_hh1,
    const float* __restrict__ b_ih1, const float* __restrict__ b_hh1,
    const float* __restrict__ fc_W, const float* __restrict__ fc_b,
    float* __restrict__ out)
{
    const int tid = threadIdx.x;
    const int w = tid >> 6;          // 0..7
    const int l = tid & 63;
    const int q = l >> 4, c = l & 15;
    const int b0 = blockIdx.x * 16;
    const bool isL1 = (w < 4);       // waves 0-3: layer 1; waves 4-7: layer 2
    const int m = w & 3;             // M-slice (rows 16m..16m+15)
    const int row = m * 16 + c;

    __shared__ unsigned long long h1buf[2][4][64];   // [dbuf][ktile][lane]
    __shared__ unsigned long long h2buf[2][4][64];
    __shared__ float fcpart[4][16];

    // ---- role-specific weight A-frags (A row = `row`, k = q*4+e) ----
    half4 A0 = mkh4(0u, 0u);         // L1 only: W_ih0 frag (K-tile 0, k>=5 zero)
    half4 AH[4], AI[4];              // L1: AH=W_hh0 ; L2: AI=W_ih1, AH=W_hh1
    f32x4 bc;                        // bias C-init for own rows
    if (isL1) {
        unsigned a0 = 0, a1 = 0;
        const float* p = W_ih0 + row * In;           // [64][5] row-major
        if (q == 0)      { a0 = pk(p[0], p[1]); a1 = pk(p[2], p[3]); }
        else if (q == 1) { a0 = pk(p[4], 0.f); }
        A0 = mkh4(a0, a1);
        #pragma unroll
        for (int kt = 0; kt < 4; ++kt) {
            const int off = row * Hn + kt * 16 + q * 4;
            float4 v0 = *reinterpret_cast<const float4*>(W_hh0 + off);
            AH[kt] = mkh4(pk(v0.x, v0.y), pk(v0.z, v0.w));
            AI[kt] = mkh4(0u, 0u);
        }
        #pragma unroll
        for (int r = 0; r < 4; ++r) {
            const int rr = m * 16 + q * 4 + r;
            bc[r] = b_ih0[rr] + b_hh0[rr];
        }
    } else {
        #pragma unroll
        for (int kt = 0; kt < 4; ++kt) {
            const int off = row * Hn + kt * 16 + q * 4;
            float4 v1 = *reinterpret_cast<const float4*>(W_ih1 + off);
            AI[kt] = mkh4(pk(v1.x, v1.y), pk(v1.z, v1.w));
            float4 v2 = *reinterpret_cast<const float4*>(W_hh1 + off);
            AH[kt] = mkh4(pk(v2.x, v2.y), pk(v2.z, v2.w));
        }
        #pragma unroll
        for (int r = 0; r < 4; ++r) {
            const int rr = m * 16 + q * 4 + r;
            bc[r] = b_ih1[rr] + b_hh1[rr];
        }
    }

    // ---- state (B-frags, register-carried) ----
    unsigned long long h1B[4] = {0, 0, 0, 0};   // H1[t]   (all waves)
    unsigned long long h2B[4] = {0, 0, 0, 0};   // H2[t-1] (L2 waves)
    f32x4 h2v = {0.f, 0.f, 0.f, 0.f};           // own H2 rows, f32 (fc)

    const float* xrow = x + (size_t)(b0 + c) * Tn * In;
    float nx0 = 0.f, nx1 = 0.f, nx2 = 0.f, nx3 = 0.f, nx4 = 0.f;
    if (isL1) {
        if (q == 0)      { nx0 = xrow[0]; nx1 = xrow[1]; nx2 = xrow[2]; nx3 = xrow[3]; }
        else if (q == 1) { nx4 = xrow[4]; }
    }

    const f32x4 zero = {0.f, 0.f, 0.f, 0.f};

    #pragma unroll 1
    for (int t = 0; t <= Tn; ++t) {
        if (isL1) {
            if (t < Tn) {   // compute H1[t+1] = tanh(Wih0 x_t + Whh0 H1[t] + b0)
                unsigned r0 = (q == 0) ? pk(nx0, nx1) : ((q == 1) ? pk(nx4, 0.f) : 0u);
                unsigned r1 = (q == 0) ? pk(nx2, nx3) : 0u;
                const half4 XF = mkh4(r0, r1);
                // prefetch x_{t+1} under this step's compute (clamped)
                const int tn = (t + 1 < Tn) ? (t + 1) : (Tn - 1);
                const float* xp = xrow + tn * In;
                if (q == 0)      { nx0 = xp[0]; nx1 = xp[1]; nx2 = xp[2]; nx3 = xp[3]; }
                else if (q == 1) { nx4 = xp[4]; }

                // 3 parallel chains, depth 2
                f32x4 cA = MFMA16(A0, XF, bc);
                cA = MFMA16(AH[0], h4of(h1B[0]), cA);
                f32x4 cB = MFMA16(AH[1], h4of(h1B[1]), zero);
                cB = MFMA16(AH[2], h4of(h1B[2]), cB);
                f32x4 cC = MFMA16(AH[3], h4of(h1B[3]), zero);
                f32x4 s = (cA + cB) + cC;
                float t0 = fast_tanh(s[0]), t1 = fast_tanh(s[1]);
                float t2 = fast_tanh(s[2]), t3 = fast_tanh(s[3]);
                h1buf[t & 1][m][l] =
                    (unsigned long long)pk(t0, t1) | ((unsigned long long)pk(t2, t3) << 32);
            }
        } else {
            if (t > 0) {    // compute H2[t] = tanh(Wih1 H1[t] + Whh1 H2[t-1] + b1)
                // 4 parallel chains, depth 2
                f32x4 aA = MFMA16(AI[0], h4of(h1B[0]), bc);
                aA = MFMA16(AI[1], h4of(h1B[1]), aA);
                f32x4 aB = MFMA16(AI[2], h4of(h1B[2]), zero);
                aB = MFMA16(AI[3], h4of(h1B[3]), aB);
                f32x4 aC = MFMA16(AH[0], h4of(h2B[0]), zero);
                aC = MFMA16(AH[1], h4of(h2B[1]), aC);
                f32x4 aD = MFMA16(AH[2], h4of(h2B[2]), zero);
                aD = MFMA16(AH[3], h4of(h2B[3]), aD);
                f32x4 s = (aA + aB) + (aC + aD);
                h2v[0] = fast_tanh(s[0]); h2v[1] = fast_tanh(s[1]);
                h2v[2] = fast_tanh(s[2]); h2v[3] = fast_tanh(s[3]);
                h2buf[t & 1][m][l] =
                    (unsigned long long)pk(h2v[0], h2v[1]) |
                    ((unsigned long long)pk(h2v[2], h2v[3]) << 32);
            } else {
                h2buf[0][m][l] = 0ULL;   // H2[0] = 0
            }
        }

        __syncthreads();

        if (t < Tn) {   // all waves: pick up H1[t+1]
            #pragma unroll
            for (int kt = 0; kt < 4; ++kt) h1B[kt] = h1buf[t & 1][kt][l];
        }
        if (!isL1) {    // L2: pick up H2[t]
            #pragma unroll
            for (int kt = 0; kt < 4; ++kt) h2B[kt] = h2buf[t & 1][kt][l];
        }
    }

    // ---- fc: out[b0+c] = sum_k fc_W[k] * H2[T][k][c] + fc_b ----
    if (!isL1) {
        float s = 0.f;
        #pragma unroll
        for (int e = 0; e < 4; ++e)
            s += fc_W[m * 16 + q * 4 + e] * h2v[e];
        s += __shfl_xor(s, 16, 64);
        s += __shfl_xor(s, 32, 64);
        if (l < 16) fcpart[m][l] = s;
    }
    __syncthreads();
    if (tid < 16)
        out[b0 + tid] = fcpart[0][tid] + fcpart[1][tid] + fcpart[2][tid]
                      + fcpart[3][tid] + fc_b[0];
}

extern "C" void kernel_launch(void* const* d_in, const int* in_sizes, int n_in,
                              void* d_out, int out_size, void* d_ws, size_t ws_size,
                              hipStream_t stream) {
    const float* x     = (const float*)d_in[0];
    const float* W_ih0 = (const float*)d_in[1];
    const float* W_hh0 = (const float*)d_in[2];
    const float* b_ih0 = (const float*)d_in[3];
    const float* b_hh0 = (const float*)d_in[4];
    const float* W_ih1 = (const float*)d_in[5];
    const float* W_hh1 = (const float*)d_in[6];
    const float* b_ih1 = (const float*)d_in[7];
    const float* b_hh1 = (const float*)d_in[8];
    const float* fc_W  = (const float*)d_in[9];
    const float* fc_b  = (const float*)d_in[10];
    float* out = (float*)d_out;

    dim3 grid(Bn / 16);   // 128 blocks; 8 waves/block (4x L1 + 4x L2)
    dim3 block(512);
    hipLaunchKernelGGL(rnn2_pipe, grid, block, 0, stream,
                       x, W_ih0, W_hh0, b_ih0, b_hh0,
                       W_ih1, W_hh1, b_ih1, b_hh1, fc_W, fc_b, out);
}

// Round 13
// 307.485 us; speedup vs baseline: 2.8748x; 1.0082x over previous
//
#include <hip/hip_runtime.h>

// 2-layer tanh RNN, B=2048 T=512 I=5 H=64 O=1 — MFMA, layer-specialized
// wave pipeline + no-vmcnt-drain barrier + 2-deep x prefetch.
//
// R12 post-mortem: 252us = 1180 cyc/iter vs ~550 structural. The gap is
// __syncthreads()'s s_waitcnt vmcnt(0) draining the x prefetch (L3/HBM
// latency 500-900cyc) at EVERY barrier. No cross-wave global communication
// exists -> barrier only needs lgkmcnt(0). Raw s_barrier keeps x loads in
// flight across iterations (AITER "vmcnt never 0" pattern); 2-iteration
// register prefetch pipeline (named sets, statically indexed) hides even
// cold-miss latency.
//
// Waves 0-3: H1[t+1] = tanh(Wih0 x_{t+1}... (M-split, 5 MFMA, 3 chains)
// Waves 4-7: H2[t]   = tanh(Wih1 H1[t] + Whh1 H2[t-1] + b1) (8 MFMA, 4 chains)
// One lgkm-barrier/iter, double-buffered LDS exchange via the free C->B
// layout identity (C/D row == B k-slot at the same lane).

constexpr int Bn = 2048;
constexpr int Tn = 512;
constexpr int In = 5;
constexpr int Hn = 64;

typedef _Float16 half4 __attribute__((ext_vector_type(4)));
typedef float f32x4 __attribute__((ext_vector_type(4)));

#define MFMA16(A, B, C) __builtin_amdgcn_mfma_f32_16x16x16f16((A), (B), (C), 0, 0, 0)

__device__ __forceinline__ unsigned pk(float a, float b) {   // 2x f32 -> packed f16 (RNE)
    union { _Float16 h[2]; unsigned u; } z;
    z.h[0] = (_Float16)a; z.h[1] = (_Float16)b;
    return z.u;
}
__device__ __forceinline__ half4 mkh4(unsigned a, unsigned b) {
    union { unsigned u[2]; half4 h; } z; z.u[0] = a; z.u[1] = b; return z.h;
}
__device__ __forceinline__ half4 h4of(unsigned long long v) {
    union { unsigned long long q; half4 h; } z; z.q = v; return z.h;
}

// tanh(v) = (e-1)/(e+1), e = 2^(2*log2e*v); med3 clamp stops overflow.
__device__ __forceinline__ float fast_tanh(float v) {
    v = __builtin_amdgcn_fmed3f(v, -15.f, 15.f);
    float e = __builtin_amdgcn_exp2f(v * 2.885390082f);
    return (e - 1.f) * __builtin_amdgcn_rcpf(e + 1.f);
}

// Barrier that does NOT drain vmcnt: LDS exchange needs lgkmcnt(0) only.
// "memory" clobber keeps ds_write before / ds_read after; global loads fly.
__device__ __forceinline__ void barrier_lds() {
    asm volatile("s_waitcnt lgkmcnt(0)\n\ts_barrier" ::: "memory");
}

// One pipeline iteration. PX0..PX4 = this iteration's x registers (set for
// step T), refilled with x[T+2] after consumption (2-deep pipeline).
#define STEP(T, PX0, PX1, PX2, PX3, PX4)                                      \
  do {                                                                        \
    const int t_ = (T);                                                       \
    if (isL1) {                                                               \
        unsigned r0 = (q == 0) ? pk(PX0, PX1) : ((q == 1) ? pk(PX4, 0.f) : 0u); \
        unsigned r1 = (q == 0) ? pk(PX2, PX3) : 0u;                           \
        const half4 XF = mkh4(r0, r1);                                        \
        const int tn_ = (t_ + 2 < Tn) ? (t_ + 2) : (Tn - 1);                  \
        const float* xp_ = xrow + tn_ * In;                                   \
        if (q == 0)      { PX0 = xp_[0]; PX1 = xp_[1]; PX2 = xp_[2]; PX3 = xp_[3]; } \
        else if (q == 1) { PX4 = xp_[4]; }                                    \
        f32x4 cA = MFMA16(A0, XF, bc);                                        \
        cA = MFMA16(AH[0], h4of(h1B[0]), cA);                                 \
        f32x4 cB = MFMA16(AH[1], h4of(h1B[1]), zero);                         \
        cB = MFMA16(AH[2], h4of(h1B[2]), cB);                                 \
        f32x4 cC = MFMA16(AH[3], h4of(h1B[3]), zero);                         \
        f32x4 s = (cA + cB) + cC;                                             \
        float t0 = fast_tanh(s[0]), t1 = fast_tanh(s[1]);                     \
        float t2 = fast_tanh(s[2]), t3 = fast_tanh(s[3]);                     \
        h1buf[t_ & 1][m][l] =                                                 \
            (unsigned long long)pk(t0, t1) | ((unsigned long long)pk(t2, t3) << 32); \
    } else {                                                                  \
        if (t_ > 0) {                                                         \
            f32x4 aA = MFMA16(AI[0], h4of(h1B[0]), bc);                       \
            aA = MFMA16(AI[1], h4of(h1B[1]), aA);                             \
            f32x4 aB = MFMA16(AI[2], h4of(h1B[2]), zero);                     \
            aB = MFMA16(AI[3], h4of(h1B[3]), aB);                             \
            f32x4 aC = MFMA16(AH[0], h4of(h2B[0]), zero);                     \
            aC = MFMA16(AH[1], h4of(h2B[1]), aC);                             \
            f32x4 aD = MFMA16(AH[2], h4of(h2B[2]), zero);                     \
            aD = MFMA16(AH[3], h4of(h2B[3]), aD);                             \
            f32x4 s = (aA + aB) + (aC + aD);                                  \
            h2v[0] = fast_tanh(s[0]); h2v[1] = fast_tanh(s[1]);               \
            h2v[2] = fast_tanh(s[2]); h2v[3] = fast_tanh(s[3]);               \
            h2buf[t_ & 1][m][l] =                                             \
                (unsigned long long)pk(h2v[0], h2v[1]) |                      \
                ((unsigned long long)pk(h2v[2], h2v[3]) << 32);               \
        } else {                                                              \
            h2buf[0][m][l] = 0ULL;                                            \
        }                                                                     \
    }                                                                         \
    barrier_lds();                                                            \
    _Pragma("unroll")                                                         \
    for (int kt = 0; kt < 4; ++kt) h1B[kt] = h1buf[t_ & 1][kt][l];            \
    if (!isL1) {                                                              \
        _Pragma("unroll")                                                     \
        for (int kt = 0; kt < 4; ++kt) h2B[kt] = h2buf[t_ & 1][kt][l];        \
    }                                                                         \
  } while (0)

__global__ __launch_bounds__(512, 1) void rnn2_pipe2(
    const float* __restrict__ x,
    const float* __restrict__ W_ih0, const float* __restrict__ W_hh0,
    const float* __restrict__ b_ih0, const float* __restrict__ b_hh0,
    const float* __restrict__ W_ih1, const float* __restrict__ W_hh1,
    const float* __restrict__ b_ih1, const float* __restrict__ b_hh1,
    const float* __restrict__ fc_W, const float* __restrict__ fc_b,
    float* __restrict__ out)
{
    const int tid = threadIdx.x;
    const int w = tid >> 6;          // 0..7
    const int l = tid & 63;
    const int q = l >> 4, c = l & 15;
    const int b0 = blockIdx.x * 16;
    const bool isL1 = (w < 4);       // waves 0-3: layer 1; waves 4-7: layer 2
    const int m = w & 3;             // M-slice (rows 16m..16m+15)
    const int row = m * 16 + c;

    __shared__ unsigned long long h1buf[2][4][64];   // [dbuf][ktile][lane]
    __shared__ unsigned long long h2buf[2][4][64];
    __shared__ float fcpart[4][16];

    // ---- role-specific weight A-frags (A row = `row`, k = q*4+e) ----
    half4 A0 = mkh4(0u, 0u);         // L1 only: W_ih0 frag (K-tile 0, k>=5 zero)
    half4 AH[4], AI[4];              // L1: AH=W_hh0 ; L2: AI=W_ih1, AH=W_hh1
    f32x4 bc;                        // bias C-init for own rows
    if (isL1) {
        unsigned a0 = 0, a1 = 0;
        const float* p = W_ih0 + row * In;           // [64][5] row-major
        if (q == 0)      { a0 = pk(p[0], p[1]); a1 = pk(p[2], p[3]); }
        else if (q == 1) { a0 = pk(p[4], 0.f); }
        A0 = mkh4(a0, a1);
        #pragma unroll
        for (int kt = 0; kt < 4; ++kt) {
            const int off = row * Hn + kt * 16 + q * 4;
            float4 v0 = *reinterpret_cast<const float4*>(W_hh0 + off);
            AH[kt] = mkh4(pk(v0.x, v0.y), pk(v0.z, v0.w));
            AI[kt] = mkh4(0u, 0u);
        }
        #pragma unroll
        for (int r = 0; r < 4; ++r) {
            const int rr = m * 16 + q * 4 + r;
            bc[r] = b_ih0[rr] + b_hh0[rr];
        }
    } else {
        #pragma unroll
        for (int kt = 0; kt < 4; ++kt) {
            const int off = row * Hn + kt * 16 + q * 4;
            float4 v1 = *reinterpret_cast<const float4*>(W_ih1 + off);
            AI[kt] = mkh4(pk(v1.x, v1.y), pk(v1.z, v1.w));
            float4 v2 = *reinterpret_cast<const float4*>(W_hh1 + off);
            AH[kt] = mkh4(pk(v2.x, v2.y), pk(v2.z, v2.w));
        }
        #pragma unroll
        for (int r = 0; r < 4; ++r) {
            const int rr = m * 16 + q * 4 + r;
            bc[r] = b_ih1[rr] + b_hh1[rr];
        }
    }

    // ---- state (B-frags, register-carried) ----
    unsigned long long h1B[4] = {0, 0, 0, 0};   // H1[t]   (all waves)
    unsigned long long h2B[4] = {0, 0, 0, 0};   // H2[t-1] (L2 waves)
    f32x4 h2v = {0.f, 0.f, 0.f, 0.f};           // own H2 rows, f32 (fc)

    // ---- 2-deep x prefetch: set A = even t, set B = odd t ----
    const float* xrow = x + (size_t)(b0 + c) * Tn * In;
    float ax0 = 0.f, ax1 = 0.f, ax2 = 0.f, ax3 = 0.f, ax4 = 0.f;  // t even
    float bx0 = 0.f, bx1 = 0.f, bx2 = 0.f, bx3 = 0.f, bx4 = 0.f;  // t odd
    if (isL1) {
        if (q == 0) {
            ax0 = xrow[0];      ax1 = xrow[1];      ax2 = xrow[2];      ax3 = xrow[3];
            bx0 = xrow[In + 0]; bx1 = xrow[In + 1]; bx2 = xrow[In + 2]; bx3 = xrow[In + 3];
        } else if (q == 1) {
            ax4 = xrow[4];
            bx4 = xrow[In + 4];
        }
    }

    const f32x4 zero = {0.f, 0.f, 0.f, 0.f};

    // t = 0..511 as 256 even/odd pairs (static register-set selection)
    #pragma unroll 1
    for (int k = 0; k < Tn / 2; ++k) {
        STEP(2 * k,     ax0, ax1, ax2, ax3, ax4);
        STEP(2 * k + 1, bx0, bx1, bx2, bx3, bx4);
    }

    // epilogue t = 512: L2 computes H2[512] into registers only (no exchange
    // needed afterwards — fc consumes h2v directly).
    if (!isL1) {
        f32x4 aA = MFMA16(AI[0], h4of(h1B[0]), bc);
        aA = MFMA16(AI[1], h4of(h1B[1]), aA);
        f32x4 aB = MFMA16(AI[2], h4of(h1B[2]), zero);
        aB = MFMA16(AI[3], h4of(h1B[3]), aB);
        f32x4 aC = MFMA16(AH[0], h4of(h2B[0]), zero);
        aC = MFMA16(AH[1], h4of(h2B[1]), aC);
        f32x4 aD = MFMA16(AH[2], h4of(h2B[2]), zero);
        aD = MFMA16(AH[3], h4of(h2B[3]), aD);
        f32x4 s = (aA + aB) + (aC + aD);
        h2v[0] = fast_tanh(s[0]); h2v[1] = fast_tanh(s[1]);
        h2v[2] = fast_tanh(s[2]); h2v[3] = fast_tanh(s[3]);

        float fs = 0.f;
        #pragma unroll
        for (int e = 0; e < 4; ++e)
            fs += fc_W[m * 16 + q * 4 + e] * h2v[e];
        fs += __shfl_xor(fs, 16, 64);
        fs += __shfl_xor(fs, 32, 64);
        if (l < 16) fcpart[m][l] = fs;
    }
    __syncthreads();
    if (tid < 16)
        out[b0 + tid] = fcpart[0][tid] + fcpart[1][tid] + fcpart[2][tid]
                      + fcpart[3][tid] + fc_b[0];
}

extern "C" void kernel_launch(void* const* d_in, const int* in_sizes, int n_in,
                              void* d_out, int out_size, void* d_ws, size_t ws_size,
                              hipStream_t stream) {
    const float* x     = (const float*)d_in[0];
    const float* W_ih0 = (const float*)d_in[1];
    const float* W_hh0 = (const float*)d_in[2];
    const float* b_ih0 = (const float*)d_in[3];
    const float* b_hh0 = (const float*)d_in[4];
    const float* W_ih1 = (const float*)d_in[5];
    const float* W_hh1 = (const float*)d_in[6];
    const float* b_ih1 = (const float*)d_in[7];
    const float* b_hh1 = (const float*)d_in[8];
    const float* fc_W  = (const float*)d_in[9];
    const float* fc_b  = (const float*)d_in[10];
    float* out = (float*)d_out;

    dim3 grid(Bn / 16);   // 128 blocks; 8 waves/block (4x L1 + 4x L2)
    dim3 block(512);
    hipLaunchKernelGGL(rnn2_pipe2, grid, block, 0, stream,
                       x, W_ih0, W_hh0, b_ih0, b_hh0,
                       W_ih1, W_hh1, b_ih1, b_hh1, fc_W, fc_b, out);
}